// Round 1
// baseline (1238.236 us; speedup 1.0000x reference)
//
#include <hip/hip_runtime.h>
#include <math.h>

constexpr int N  = 60000;
constexpr int F  = 256;
constexpr int H  = 128;
constexpr int C  = 256;
constexpr int E  = 600000;
constexpr int ET = 1500;
constexpr int NB = (N + 1023) / 1024;  // 59 scan blocks

// ---------------- CSR construction ----------------
__global__ void hg_cell_hist(const int* __restrict__ cdst, int* __restrict__ deg) {
  int e = blockIdx.x * 256 + threadIdx.x;
  if (e < E) atomicAdd(&deg[cdst[e]], 1);
}

__global__ __launch_bounds__(256) void hg_scan1(const int* __restrict__ deg, int* __restrict__ off,
                                                int* __restrict__ btot, int n) {
  int b = blockIdx.x, t = threadIdx.x;
  int i0 = b * 1024 + t * 4;
  __shared__ int sums[256];
  int d0 = 0, d1 = 0, d2 = 0, d3 = 0;
  if (i0 + 3 < n) {
    int4 dd = *(const int4*)&deg[i0];
    d0 = dd.x; d1 = dd.y; d2 = dd.z; d3 = dd.w;
  } else {
    if (i0     < n) d0 = deg[i0];
    if (i0 + 1 < n) d1 = deg[i0 + 1];
    if (i0 + 2 < n) d2 = deg[i0 + 2];
    if (i0 + 3 < n) d3 = deg[i0 + 3];
  }
  int s = d0 + d1 + d2 + d3;
  sums[t] = s;
  __syncthreads();
  for (int ofs = 1; ofs < 256; ofs <<= 1) {
    int v = (t >= ofs) ? sums[t - ofs] : 0;
    __syncthreads();
    sums[t] += v;
    __syncthreads();
  }
  int excl = sums[t] - s;
  if (t == 255) btot[b] = sums[t];
  int run = excl;
  if (i0     < n) off[i0]     = run; run += d0;
  if (i0 + 1 < n) off[i0 + 1] = run; run += d1;
  if (i0 + 2 < n) off[i0 + 2] = run; run += d2;
  if (i0 + 3 < n) off[i0 + 3] = run;
}

__global__ void hg_scan2(int* __restrict__ btot, int* __restrict__ off) {
  __shared__ int s[64];
  int t = threadIdx.x;
  s[t] = (t < NB) ? btot[t] : 0;
  __syncthreads();
  if (t == 0) {
    int r = 0;
    for (int i = 0; i < NB; ++i) { int v = s[i]; s[i] = r; r += v; }
    off[N] = r;
  }
  __syncthreads();
  if (t < NB) btot[t] = s[t];
}

__global__ void hg_scan3(int* __restrict__ off, const int* __restrict__ btot, int n) {
  int b = blockIdx.x;
  int addv = btot[b];
  int i0 = b * 1024 + threadIdx.x * 4;
#pragma unroll
  for (int r = 0; r < 4; ++r)
    if (i0 + r < n) off[i0 + r] += addv;
}

__global__ void hg_cell_scatter(const int* __restrict__ csrc, const int* __restrict__ cdst,
                                const int* __restrict__ off, int* __restrict__ cur, int* __restrict__ csr) {
  int e = blockIdx.x * 256 + threadIdx.x;
  if (e < E) {
    int d = cdst[e];
    int p = atomicAdd(&cur[d], 1);
    csr[off[d] + p] = csrc[e];
  }
}

__global__ void hg_clu_hist(const int* __restrict__ lab, int* __restrict__ cnt) {
  int i = blockIdx.x * 256 + threadIdx.x;
  if (i < N) atomicAdd(&cnt[lab[i]], 1);
}

__global__ void hg_clu_scan(const int* __restrict__ cnt, int* __restrict__ coff) {
  __shared__ int s[256];
  int t = threadIdx.x;
  int v0 = cnt[t];
  s[t] = v0;
  __syncthreads();
  for (int ofs = 1; ofs < 256; ofs <<= 1) {
    int v = (t >= ofs) ? s[t - ofs] : 0;
    __syncthreads();
    s[t] += v;
    __syncthreads();
  }
  coff[t + 1] = s[t];
  if (t == 0) coff[0] = 0;
}

__global__ void hg_clu_scatter(const int* __restrict__ lab, const int* __restrict__ coff,
                               int* __restrict__ cur, int* __restrict__ list) {
  int i = blockIdx.x * 256 + threadIdx.x;
  if (i < N) {
    int c = lab[i];
    int p = atomicAdd(&cur[c], 1);
    list[coff[c] + p] = i;
  }
}

__global__ void hg_tissue_dinv(const int* __restrict__ tdst, float* __restrict__ dinv) {
  __shared__ int hst[256];
  int t = threadIdx.x;
  hst[t] = 0;
  __syncthreads();
  for (int e = t; e < ET; e += 256) atomicAdd(&hst[tdst[e]], 1);
  __syncthreads();
  dinv[t] = 1.f / sqrtf((float)(hst[t] + 1));  // +1 self-loop
}

// ---------------- weight transposes ----------------
struct TArgs { const float* src[9]; float* dst[9]; int R[9]; int Cc[9]; };

__global__ __launch_bounds__(256) void hg_transpose9(TArgs a) {
  int job = blockIdx.y;
  int R = a.R[job], Cc = a.Cc[job];
  int total = R * Cc;
  const float* s = a.src[job];
  float* d = a.dst[job];
  for (int idx = blockIdx.x * 256 + threadIdx.x; idx < total; idx += gridDim.x * 256) {
    int cI = idx / R, r = idx - cI * R;
    d[idx] = s[r * Cc + cI];  // dst[input][output]
  }
}

// ---------------- tissue node init: per-cluster feature mean ----------------
__global__ __launch_bounds__(256) void hg_tissue_mean(const float* __restrict__ feat,
                                                      const int* __restrict__ list,
                                                      const int* __restrict__ coff,
                                                      float* __restrict__ tx) {
  int c = blockIdx.x, t = threadIdx.x;
  int s0 = coff[c], n = coff[c + 1] - s0;
  float acc = 0.f;
#pragma unroll 4
  for (int i = 0; i < n; ++i) acc += feat[(size_t)list[s0 + i] * F + t];
  tx[c * F + t] = acc / fmaxf((float)n, 1.f);
}

// ---------------- fp32 GEMM: out[m][j] = sum_k A[m][k]*W[j][k] + bias[j], Jout=128 ----------------
template <int K>
__global__ __launch_bounds__(256) void hg_gemm128(const float* __restrict__ A, const float* __restrict__ W,
                                                  const float* __restrict__ bias, float* __restrict__ outp, int M) {
  __shared__ float Alds[64][68];
  __shared__ float Wlds[64][132];
  const int t = threadIdx.x;
  const int tx = t & 15, ty = t >> 4;
  const int m0 = blockIdx.x * 64;
  float acc[4][8];
#pragma unroll
  for (int r = 0; r < 4; ++r)
#pragma unroll
    for (int cc = 0; cc < 8; ++cc) acc[r][cc] = 0.f;

  for (int kc = 0; kc < K; kc += 64) {
#pragma unroll
    for (int i = 0; i < 16; ++i) {  // stage A (64 rows x 64 k), transposed
      int idx = t + i * 256;
      int m = idx >> 6, k = idx & 63;
      int gm = m0 + m;
      Alds[k][m] = (gm < M) ? A[(size_t)gm * K + kc + k] : 0.f;
    }
#pragma unroll
    for (int i = 0; i < 32; ++i) {  // stage W (128 j x 64 k), transposed
      int idx = t + i * 256;
      int j = idx >> 6, k = idx & 63;
      Wlds[k][j] = W[(size_t)j * K + kc + k];
    }
    __syncthreads();
#pragma unroll 4
    for (int kk = 0; kk < 64; ++kk) {
      const float4 av  = *(const float4*)&Alds[kk][ty * 4];
      const float4 bv0 = *(const float4*)&Wlds[kk][tx * 8];
      const float4 bv1 = *(const float4*)&Wlds[kk][tx * 8 + 4];
      const float ar[4] = {av.x, av.y, av.z, av.w};
      const float br[8] = {bv0.x, bv0.y, bv0.z, bv0.w, bv1.x, bv1.y, bv1.z, bv1.w};
#pragma unroll
      for (int r = 0; r < 4; ++r)
#pragma unroll
        for (int cc = 0; cc < 8; ++cc) acc[r][cc] = fmaf(ar[r], br[cc], acc[r][cc]);
    }
    __syncthreads();
  }
  float bv[8];
#pragma unroll
  for (int cc = 0; cc < 8; ++cc) bv[cc] = bias ? bias[tx * 8 + cc] : 0.f;
#pragma unroll
  for (int r = 0; r < 4; ++r) {
    int gm = m0 + ty * 4 + r;
    if (gm < M) {
      float* op = outp + (size_t)gm * 128 + tx * 8;
      *(float4*)op       = make_float4(acc[r][0] + bv[0], acc[r][1] + bv[1], acc[r][2] + bv[2], acc[r][3] + bv[3]);
      *(float4*)(op + 4) = make_float4(acc[r][4] + bv[4], acc[r][5] + bv[5], acc[r][6] + bv[6], acc[r][7] + bv[7]);
    }
  }
}

// ---------------- GAT attention coefficients: a_s/a_d [rows,8] ----------------
__global__ __launch_bounds__(256) void hg_gat_coef(const float* __restrict__ hp, const float* __restrict__ avs,
                                                   const float* __restrict__ avd, float* __restrict__ a_s,
                                                   float* __restrict__ a_d, int rows) {
  int row = blockIdx.x * 2 + (threadIdx.x >> 7);
  int c = threadIdx.x & 127;
  if (row >= rows) return;
  float v = hp[(size_t)row * 128 + c];
  float ps = v * avs[c], pd = v * avd[c];
#pragma unroll
  for (int mk = 8; mk >= 1; mk >>= 1) {
    ps += __shfl_xor(ps, mk);
    pd += __shfl_xor(pd, mk);
  }
  if ((c & 15) == 0) {
    a_s[row * 8 + (c >> 4)] = ps;
    a_d[row * 8 + (c >> 4)] = pd;
  }
}

// ---------------- GAT aggregation (per-dst online softmax), block = 1 node x 128 thr ----------------
#define MAXE 192
__global__ __launch_bounds__(128) void hg_gat_agg(const float* __restrict__ hproj, const float* __restrict__ a_s,
                                                  const float* __restrict__ a_d, const int* __restrict__ remap,
                                                  const int* __restrict__ off, const int* __restrict__ csr,
                                                  const float* __restrict__ bias, float* __restrict__ outh) {
  int node = blockIdx.x;
  int t = threadIdx.x;
  __shared__ int srcs[MAXE];
  __shared__ float slds[MAXE][8];
  __shared__ float red[16][8];
  __shared__ float adl[8], asl[8], cmx[8];
  int o0 = off[node], o1 = off[node + 1];
  int deg = o1 - o0;
  int dl = remap ? remap[node] : node;
  if (t < 8) { adl[t] = a_d[dl * 8 + t]; asl[t] = a_s[dl * 8 + t]; }
  __syncthreads();
  const int h = t >> 4;               // accumulate layout
  const int g = t >> 3, h8 = t & 7;   // score layout
  const float adh8 = adl[h8];
  float m = -INFINITY, z = 0.f, acc = 0.f;

  for (int cb = 0; cb < deg; cb += MAXE) {
    int len = min(MAXE, deg - cb);
    for (int e = t; e < len; e += 128) {
      int s = csr[o0 + cb + e];
      srcs[e] = remap ? remap[s] : s;
    }
    __syncthreads();
    float lm = -INFINITY;
    for (int e = g; e < len; e += 16) {
      float s = a_s[srcs[e] * 8 + h8] + adh8;
      s = s > 0.f ? s : 0.2f * s;  // leaky_relu(0.2)
      slds[e][h8] = s;
      lm = fmaxf(lm, s);
    }
    red[g][h8] = lm;
    __syncthreads();
    if (t < 8) {
      float m2 = -INFINITY;
#pragma unroll
      for (int i = 0; i < 16; ++i) m2 = fmaxf(m2, red[i][t]);
      cmx[t] = m2;
    }
    __syncthreads();
    float nm = fmaxf(m, cmx[h]);
    float sc = expf(m - nm);  // m=-inf -> 0
    z *= sc; acc *= sc; m = nm;
#pragma unroll 2
    for (int e = 0; e < len; ++e) {
      float w = expf(slds[e][h] - m);
      acc = fmaf(w, hproj[(size_t)srcs[e] * 128 + t], acc);
      z += w;
    }
    __syncthreads();
  }
  // self-loop
  {
    float s = asl[h] + adl[h];
    s = s > 0.f ? s : 0.2f * s;
    float nm = fmaxf(m, s);
    float sc = expf(m - nm);
    z *= sc; acc *= sc; m = nm;
    float w = expf(s - m);
    z += w;
    acc = fmaf(w, hproj[(size_t)dl * 128 + t], acc);
  }
  float o = acc / z + bias[t];
  o = o > 0.f ? o : expm1f(o);  // ELU
  outh[(size_t)node * 128 + t] = o;
}

// ---------------- tissue GCN + fused q projection ----------------
__global__ __launch_bounds__(128) void hg_gcn_q(const float* __restrict__ th, const int* __restrict__ tsrc,
                                                const int* __restrict__ tdst, const float* __restrict__ dinv,
                                                const float* __restrict__ gcnb, const float* __restrict__ Wqt,
                                                const float* __restrict__ bq, float* __restrict__ tish,
                                                float* __restrict__ q) {
  int c = blockIdx.x, t = threadIdx.x;
  __shared__ int esrc[128], edst[128];
  __shared__ float trow[128];
  float dc = dinv[c];
  float acc = th[c * 128 + t] * dc * dc;  // self-loop
  for (int base = 0; base < ET; base += 128) {
    int len = min(128, ET - base);
    if (t < len) { esrc[t] = tsrc[base + t]; edst[t] = tdst[base + t]; }
    __syncthreads();
    for (int e = 0; e < len; ++e) {
      if (edst[e] == c) acc += th[esrc[e] * 128 + t] * dinv[esrc[e]] * dc;
    }
    __syncthreads();
  }
  float vv = fmaxf(acc + gcnb[t], 0.f);
  tish[c * 128 + t] = vv;
  trow[t] = vv;
  __syncthreads();
  float qa = bq[t];
#pragma unroll 4
  for (int kk = 0; kk < 128; ++kk) qa = fmaf(trow[kk], Wqt[kk * 128 + t], qa);
  q[c * 128 + t] = qa * 0.25f;  // 1/sqrt(DH)
}

// ---------------- bottom-up attention scores ----------------
__global__ __launch_bounds__(256) void hg_bu_satt(const float* __restrict__ kk, const float* __restrict__ q,
                                                  const int* __restrict__ lab, float* __restrict__ s_att, int rows) {
  int row = blockIdx.x * 2 + (threadIdx.x >> 7);
  int c = threadIdx.x & 127;
  if (row >= rows) return;
  float p = kk[(size_t)row * 128 + c] * q[(size_t)lab[row] * 128 + c];
#pragma unroll
  for (int mk = 8; mk >= 1; mk >>= 1) p += __shfl_xor(p, mk);
  if ((c & 15) == 0) s_att[row * 8 + (c >> 4)] = p;
}

// ---------------- bottom-up per-cluster softmax + context ----------------
__global__ __launch_bounds__(128) void hg_bu_ctx(const float* __restrict__ s_att, const float* __restrict__ v,
                                                 const int* __restrict__ list, const int* __restrict__ coff,
                                                 float* __restrict__ ctx) {
  int c = blockIdx.x, t = threadIdx.x;
  int s0 = coff[c], n = coff[c + 1] - s0;
  __shared__ float red[16][8];
  __shared__ float mh[8];
  int g = t >> 3, h8 = t & 7;
  float lm = -INFINITY;
  for (int i = g; i < n; i += 16) lm = fmaxf(lm, s_att[(size_t)list[s0 + i] * 8 + h8]);
  red[g][h8] = lm;
  __syncthreads();
  if (t < 8) {
    float m2 = -INFINITY;
#pragma unroll
    for (int i = 0; i < 16; ++i) m2 = fmaxf(m2, red[i][t]);
    mh[t] = m2;
  }
  __syncthreads();
  int h = t >> 4;
  float m = mh[h], z = 0.f, acc = 0.f;
#pragma unroll 4
  for (int i = 0; i < n; ++i) {
    int cell = list[s0 + i];
    float w = expf(s_att[(size_t)cell * 8 + h] - m);
    acc = fmaf(w, v[(size_t)cell * 128 + t], acc);
    z += w;
  }
  ctx[c * 128 + t] = (n > 0) ? acc / z : 0.f;
}

// ---------------- per-cluster chain: Wo, top-down, GRU, (next-layer GAT proj) ----------------
__global__ __launch_bounds__(128) void hg_cluster_update(
    const float* __restrict__ ctx, const float* __restrict__ Wot, const float* __restrict__ bo,
    const float* __restrict__ tdWvt, const float* __restrict__ tdbv, const float* __restrict__ tdWot,
    const float* __restrict__ tdbo, const float* __restrict__ Wiht, const float* __restrict__ bih,
    const float* __restrict__ Whht, const float* __restrict__ bhh, const float* __restrict__ gatWt,
    const float* __restrict__ as2, const float* __restrict__ ad2, float* __restrict__ tish,
    float* __restrict__ ccell, float* __restrict__ hprojc, float* __restrict__ a_s2, float* __restrict__ a_d2) {
  int c = blockIdx.x, t = threadIdx.x;
  __shared__ float b0[128], b1[128], b2[128];
  b0[t] = ctx[c * 128 + t];
  __syncthreads();
  float acc = bo[t];
#pragma unroll 4
  for (int kk = 0; kk < 128; ++kk) acc = fmaf(b0[kk], Wot[kk * 128 + t], acc);
  tish[c * 128 + t] = acc;  // new tissue_h
  __syncthreads();
  b1[t] = acc;
  __syncthreads();
  float a1v = tdbv[t];
#pragma unroll 4
  for (int kk = 0; kk < 128; ++kk) a1v = fmaf(b1[kk], tdWvt[kk * 128 + t], a1v);
  b2[t] = a1v;
  __syncthreads();
  float a2v = tdbo[t];
#pragma unroll 4
  for (int kk = 0; kk < 128; ++kk) a2v = fmaf(b2[kk], tdWot[kk * 128 + t], a2v);
  __syncthreads();
  b0[t] = a2v;  // td row == cell_h for all cells of cluster
  __syncthreads();
  float g0 = bih[t], g1 = bih[t + 128], g2 = bih[t + 256];
#pragma unroll 2
  for (int kk = 0; kk < 128; ++kk) {
    float x = b0[kk];
    g0 = fmaf(x, Wiht[kk * 384 + t], g0);
    g1 = fmaf(x, Wiht[kk * 384 + t + 128], g1);
    g2 = fmaf(x, Wiht[kk * 384 + t + 256], g2);
  }
#pragma unroll 2
  for (int kk = 0; kk < 128; ++kk) {
    float x = b1[kk];
    int k2 = kk + 128;
    g0 = fmaf(x, Wiht[k2 * 384 + t], g0);
    g1 = fmaf(x, Wiht[k2 * 384 + t + 128], g1);
    g2 = fmaf(x, Wiht[k2 * 384 + t + 256], g2);
  }
  float h0 = bhh[t], h1v = bhh[t + 128], h2v = bhh[t + 256];
#pragma unroll 2
  for (int kk = 0; kk < 128; ++kk) {
    float x = b0[kk];
    h0  = fmaf(x, Whht[kk * 384 + t], h0);
    h1v = fmaf(x, Whht[kk * 384 + t + 128], h1v);
    h2v = fmaf(x, Whht[kk * 384 + t + 256], h2v);
  }
  float r  = 1.f / (1.f + expf(-(g0 + h0)));
  float zz = 1.f / (1.f + expf(-(g1 + h1v)));
  float nn = tanhf(g2 + r * h2v);
  float cn = (1.f - zz) * nn + zz * b0[t];
  ccell[c * 128 + t] = cn;
  if (gatWt) {
    __syncthreads();
    b2[t] = cn;
    __syncthreads();
    float hp = 0.f;
#pragma unroll 4
    for (int kk = 0; kk < 128; ++kk) hp = fmaf(b2[kk], gatWt[kk * 128 + t], hp);
    hprojc[c * 128 + t] = hp;
    float ps = hp * as2[t], pd = hp * ad2[t];
#pragma unroll
    for (int mk = 8; mk >= 1; mk >>= 1) {
      ps += __shfl_xor(ps, mk);
      pd += __shfl_xor(pd, mk);
    }
    if ((t & 15) == 0) {
      a_s2[c * 8 + (t >> 4)] = ps;
      a_d2[c * 8 + (t >> 4)] = pd;
    }
  }
}

// ---------------- readout + classifier ----------------
__global__ __launch_bounds__(256) void hg_readout(const float* __restrict__ ccell2, const float* __restrict__ tish,
                                                  const int* __restrict__ cnt, const float* __restrict__ Wc1t,
                                                  const float* __restrict__ bc1, const float* __restrict__ Wc2t,
                                                  const float* __restrict__ bc2, const float* __restrict__ Wc3,
                                                  const float* __restrict__ bc3, float* __restrict__ outp) {
  __shared__ float emb[512], h1s[256], h2s[128];
  int t = threadIdx.x;
  if (t < 128) {
    float sm = 0.f, mx = -INFINITY;
    for (int c = 0; c < C; ++c) {
      float vv = ccell2[c * 128 + t];
      int n = cnt[c];
      sm += (float)n * vv;
      if (n > 0) mx = fmaxf(mx, vv);
    }
    emb[t] = sm / (float)N;
    emb[128 + t] = mx;
  } else {
    int tt = t - 128;
    float sm = 0.f, mx = -INFINITY;
    for (int c = 0; c < C; ++c) {
      float vv = tish[c * 128 + tt];
      sm += vv;
      mx = fmaxf(mx, vv);
    }
    emb[256 + tt] = sm * (1.f / (float)C);
    emb[384 + tt] = mx;
  }
  __syncthreads();
  float a = bc1[t];
#pragma unroll 4
  for (int kk = 0; kk < 512; ++kk) a = fmaf(emb[kk], Wc1t[kk * 256 + t], a);
  h1s[t] = fmaxf(a, 0.f);
  __syncthreads();
  if (t < 128) {
    float a2 = bc2[t];
#pragma unroll 4
    for (int kk = 0; kk < 256; ++kk) a2 = fmaf(h1s[kk], Wc2t[kk * 128 + t], a2);
    h2s[t] = fmaxf(a2, 0.f);
  }
  __syncthreads();
  if (t < 4) {
    float o = bc3[t];
    for (int kk = 0; kk < 128; ++kk) o = fmaf(h2s[kk], Wc3[t * 128 + kk], o);
    outp[t] = o;
  }
}

// ---------------- host launcher ----------------
extern "C" void kernel_launch(void* const* d_in, const int* in_sizes, int n_in,
                              void* d_out, int out_size, void* d_ws, size_t ws_size,
                              hipStream_t stream) {
  (void)in_sizes; (void)n_in; (void)out_size; (void)ws_size;
  const float* feat  = (const float*)d_in[0];
  const int*   eidx  = (const int*)d_in[1];
  const int*   lab   = (const int*)d_in[2];
  const int*   tidx  = (const int*)d_in[3];
  const float* Wcp   = (const float*)d_in[4];
  const float* bcp   = (const float*)d_in[5];
  const float* Wtp   = (const float*)d_in[6];
  const float* btp   = (const float*)d_in[7];
  const float* gatW  = (const float*)d_in[8];
  const float* gasrc = (const float*)d_in[9];
  const float* gadst = (const float*)d_in[10];
  const float* gatb  = (const float*)d_in[11];
  const float* gcnW  = (const float*)d_in[12];
  const float* gcnb  = (const float*)d_in[13];
  const float* buWq  = (const float*)d_in[14];
  const float* buWk  = (const float*)d_in[15];
  const float* buWv  = (const float*)d_in[16];
  const float* bubq  = (const float*)d_in[17];
  const float* bubk  = (const float*)d_in[18];
  const float* bubv  = (const float*)d_in[19];
  const float* buWo  = (const float*)d_in[20];
  const float* bubo  = (const float*)d_in[21];
  const float* tdWv  = (const float*)d_in[22];
  const float* tdbv  = (const float*)d_in[23];
  const float* tdWo  = (const float*)d_in[24];
  const float* tdbo  = (const float*)d_in[25];
  const float* Wih   = (const float*)d_in[26];
  const float* bih   = (const float*)d_in[27];
  const float* Whh   = (const float*)d_in[28];
  const float* bhh   = (const float*)d_in[29];
  const float* Wc1   = (const float*)d_in[30];
  const float* bc1   = (const float*)d_in[31];
  const float* Wc2   = (const float*)d_in[32];
  const float* bc2   = (const float*)d_in[33];
  const float* Wc3   = (const float*)d_in[34];
  const float* bc3   = (const float*)d_in[35];
  float* outp = (float*)d_out;

  const int* csrc = eidx;
  const int* cdst = eidx + E;
  const int* tsrc = tidx;
  const int* tdst = tidx + ET;

  char* w = (char*)d_ws;
  auto alloc = [&](size_t bytes) -> void* {
    void* p = (void*)w;
    w += (bytes + 255) & ~(size_t)255;
    return p;
  };
  char* cnt0 = w;
  int* deg_cell = (int*)alloc((size_t)N * 4);
  int* cur_cell = (int*)alloc((size_t)N * 4);
  int* clu_cnt  = (int*)alloc((size_t)C * 4);
  int* clu_cur  = (int*)alloc((size_t)C * 4);
  size_t cntBytes = (size_t)(w - cnt0);
  int* off_cell = (int*)alloc((size_t)(N + 1) * 4);
  int* btot     = (int*)alloc(64 * 4);
  int* csr      = (int*)alloc((size_t)E * 4);
  int* clu_off  = (int*)alloc((size_t)(C + 1) * 4);
  int* clu_list = (int*)alloc((size_t)N * 4);
  float* dinv   = (float*)alloc((size_t)C * 4);
  float* buf1   = (float*)alloc((size_t)N * 128 * 4);
  float* buf2   = (float*)alloc((size_t)N * 128 * 4);
  float* a_s    = (float*)alloc((size_t)N * 8 * 4);
  float* a_d    = (float*)alloc((size_t)N * 8 * 4);
  float* s_att  = (float*)alloc((size_t)N * 8 * 4);
  float* tx     = (float*)alloc((size_t)C * F * 4);
  float* tish   = (float*)alloc((size_t)C * 128 * 4);
  float* thb    = (float*)alloc((size_t)C * 128 * 4);
  float* qb     = (float*)alloc((size_t)C * 128 * 4);
  float* ctxb   = (float*)alloc((size_t)C * 128 * 4);
  float* ccell  = (float*)alloc((size_t)C * 128 * 4);
  float* hprojc = (float*)alloc((size_t)C * 128 * 4);
  float* a_sc   = (float*)alloc((size_t)C * 8 * 4);
  float* a_dc   = (float*)alloc((size_t)C * 8 * 4);
  float* Wqt    = (float*)alloc(128 * 128 * 4);
  float* Wot    = (float*)alloc(128 * 128 * 4);
  float* tdWvt  = (float*)alloc(128 * 128 * 4);
  float* tdWot  = (float*)alloc(128 * 128 * 4);
  float* gatW1t = (float*)alloc(128 * 128 * 4);
  float* Wiht   = (float*)alloc(256 * 384 * 4);
  float* Whht   = (float*)alloc(128 * 384 * 4);
  float* Wc1t   = (float*)alloc(512 * 256 * 4);
  float* Wc2t   = (float*)alloc(256 * 128 * 4);

  hipMemsetAsync(cnt0, 0, cntBytes, stream);

  hg_cell_hist<<<(E + 255) / 256, 256, 0, stream>>>(cdst, deg_cell);
  hg_scan1<<<NB, 256, 0, stream>>>(deg_cell, off_cell, btot, N);
  hg_scan2<<<1, 64, 0, stream>>>(btot, off_cell);
  hg_scan3<<<NB, 256, 0, stream>>>(off_cell, btot, N);
  hg_cell_scatter<<<(E + 255) / 256, 256, 0, stream>>>(csrc, cdst, off_cell, cur_cell, csr);
  hg_clu_hist<<<(N + 255) / 256, 256, 0, stream>>>(lab, clu_cnt);
  hg_clu_scan<<<1, 256, 0, stream>>>(clu_cnt, clu_off);
  hg_clu_scatter<<<(N + 255) / 256, 256, 0, stream>>>(lab, clu_off, clu_cur, clu_list);
  hg_tissue_dinv<<<1, 256, 0, stream>>>(tdst, dinv);

  TArgs ta;
  ta.src[0] = buWq;            ta.dst[0] = Wqt;    ta.R[0] = 128; ta.Cc[0] = 128;
  ta.src[1] = buWo;            ta.dst[1] = Wot;    ta.R[1] = 128; ta.Cc[1] = 128;
  ta.src[2] = tdWv;            ta.dst[2] = tdWvt;  ta.R[2] = 128; ta.Cc[2] = 128;
  ta.src[3] = tdWo;            ta.dst[3] = tdWot;  ta.R[3] = 128; ta.Cc[3] = 128;
  ta.src[4] = gatW + 128*128;  ta.dst[4] = gatW1t; ta.R[4] = 128; ta.Cc[4] = 128;
  ta.src[5] = Wih;             ta.dst[5] = Wiht;   ta.R[5] = 384; ta.Cc[5] = 256;
  ta.src[6] = Whh;             ta.dst[6] = Whht;   ta.R[6] = 384; ta.Cc[6] = 128;
  ta.src[7] = Wc1;             ta.dst[7] = Wc1t;   ta.R[7] = 256; ta.Cc[7] = 512;
  ta.src[8] = Wc2;             ta.dst[8] = Wc2t;   ta.R[8] = 128; ta.Cc[8] = 256;
  hg_transpose9<<<dim3(64, 9), 256, 0, stream>>>(ta);

  hg_tissue_mean<<<C, 256, 0, stream>>>(feat, clu_list, clu_off, tx);
  hg_gemm128<256><<<(N + 63) / 64, 256, 0, stream>>>(feat, Wcp, bcp, buf1, N);
  hg_gemm128<256><<<(C + 63) / 64, 256, 0, stream>>>(tx, Wtp, btp, tish, C);

  // ---- layer 1 ----
  hg_gemm128<128><<<(N + 63) / 64, 256, 0, stream>>>(buf1, gatW, nullptr, buf2, N);
  hg_gat_coef<<<N / 2, 256, 0, stream>>>(buf2, gasrc, gadst, a_s, a_d, N);
  hg_gat_agg<<<N, 128, 0, stream>>>(buf2, a_s, a_d, nullptr, off_cell, csr, gatb, buf1);
  hg_gemm128<128><<<(C + 63) / 64, 256, 0, stream>>>(tish, gcnW, nullptr, thb, C);
  hg_gcn_q<<<C, 128, 0, stream>>>(thb, tsrc, tdst, dinv, gcnb, Wqt, bubq, tish, qb);
  hg_gemm128<128><<<(N + 63) / 64, 256, 0, stream>>>(buf1, buWk, bubk, buf2, N);
  hg_bu_satt<<<N / 2, 256, 0, stream>>>(buf2, qb, lab, s_att, N);
  hg_gemm128<128><<<(N + 63) / 64, 256, 0, stream>>>(buf1, buWv, bubv, buf2, N);
  hg_bu_ctx<<<C, 128, 0, stream>>>(s_att, buf2, clu_list, clu_off, ctxb);
  hg_cluster_update<<<C, 128, 0, stream>>>(ctxb, Wot, bubo, tdWvt, tdbv, tdWot, tdbo,
                                           Wiht, bih, Whht, bhh, gatW1t, gasrc + 128, gadst + 128,
                                           tish, ccell, hprojc, a_sc, a_dc);
  // ---- layer 2 ----
  hg_gat_agg<<<N, 128, 0, stream>>>(hprojc, a_sc, a_dc, lab, off_cell, csr, gatb + 128, buf1);
  hg_gemm128<128><<<(C + 63) / 64, 256, 0, stream>>>(tish, gcnW + 128 * 128, nullptr, thb, C);
  hg_gcn_q<<<C, 128, 0, stream>>>(thb, tsrc, tdst, dinv, gcnb + 128, Wqt, bubq, tish, qb);
  hg_gemm128<128><<<(N + 63) / 64, 256, 0, stream>>>(buf1, buWk, bubk, buf2, N);
  hg_bu_satt<<<N / 2, 256, 0, stream>>>(buf2, qb, lab, s_att, N);
  hg_gemm128<128><<<(N + 63) / 64, 256, 0, stream>>>(buf1, buWv, bubv, buf2, N);
  hg_bu_ctx<<<C, 128, 0, stream>>>(s_att, buf2, clu_list, clu_off, ctxb);
  hg_cluster_update<<<C, 128, 0, stream>>>(ctxb, Wot, bubo, tdWvt, tdbv, tdWot, tdbo,
                                           Wiht, bih, Whht, bhh, nullptr, nullptr, nullptr,
                                           tish, ccell, nullptr, nullptr, nullptr);

  hg_readout<<<1, 256, 0, stream>>>(ccell, tish, clu_cnt, Wc1t, bc1, Wc2t, bc2, Wc3, bc3, outp);
}

// Round 2
// 854.865 us; speedup vs baseline: 1.4485x; 1.4485x over previous
//
#include <hip/hip_runtime.h>
#include <math.h>

constexpr int N  = 60000;
constexpr int F  = 256;
constexpr int H  = 128;
constexpr int C  = 256;
constexpr int E  = 600000;
constexpr int ET = 1500;
constexpr int NB = (N + 1023) / 1024;  // 59 scan blocks

// ---------------- CSR construction ----------------
__global__ void hg_cell_hist(const int* __restrict__ cdst, int* __restrict__ deg) {
  int e = blockIdx.x * 256 + threadIdx.x;
  if (e < E) atomicAdd(&deg[cdst[e]], 1);
}

__global__ __launch_bounds__(256) void hg_scan1(const int* __restrict__ deg, int* __restrict__ off,
                                                int* __restrict__ btot, int n) {
  int b = blockIdx.x, t = threadIdx.x;
  int i0 = b * 1024 + t * 4;
  __shared__ int sums[256];
  int d0 = 0, d1 = 0, d2 = 0, d3 = 0;
  if (i0 + 3 < n) {
    int4 dd = *(const int4*)&deg[i0];
    d0 = dd.x; d1 = dd.y; d2 = dd.z; d3 = dd.w;
  } else {
    if (i0     < n) d0 = deg[i0];
    if (i0 + 1 < n) d1 = deg[i0 + 1];
    if (i0 + 2 < n) d2 = deg[i0 + 2];
    if (i0 + 3 < n) d3 = deg[i0 + 3];
  }
  int s = d0 + d1 + d2 + d3;
  sums[t] = s;
  __syncthreads();
  for (int ofs = 1; ofs < 256; ofs <<= 1) {
    int v = (t >= ofs) ? sums[t - ofs] : 0;
    __syncthreads();
    sums[t] += v;
    __syncthreads();
  }
  int excl = sums[t] - s;
  if (t == 255) btot[b] = sums[t];
  int run = excl;
  if (i0     < n) off[i0]     = run; run += d0;
  if (i0 + 1 < n) off[i0 + 1] = run; run += d1;
  if (i0 + 2 < n) off[i0 + 2] = run; run += d2;
  if (i0 + 3 < n) off[i0 + 3] = run;
}

__global__ void hg_scan2(int* __restrict__ btot, int* __restrict__ off) {
  __shared__ int s[64];
  int t = threadIdx.x;
  s[t] = (t < NB) ? btot[t] : 0;
  __syncthreads();
  if (t == 0) {
    int r = 0;
    for (int i = 0; i < NB; ++i) { int v = s[i]; s[i] = r; r += v; }
    off[N] = r;
  }
  __syncthreads();
  if (t < NB) btot[t] = s[t];
}

__global__ void hg_scan3(int* __restrict__ off, const int* __restrict__ btot, int n) {
  int b = blockIdx.x;
  int addv = btot[b];
  int i0 = b * 1024 + threadIdx.x * 4;
#pragma unroll
  for (int r = 0; r < 4; ++r)
    if (i0 + r < n) off[i0 + r] += addv;
}

__global__ void hg_cell_scatter(const int* __restrict__ csrc, const int* __restrict__ cdst,
                                const int* __restrict__ off, int* __restrict__ cur, int* __restrict__ csr) {
  int e = blockIdx.x * 256 + threadIdx.x;
  if (e < E) {
    int d = cdst[e];
    int p = atomicAdd(&cur[d], 1);
    csr[off[d] + p] = csrc[e];
  }
}

__global__ void hg_clu_hist(const int* __restrict__ lab, int* __restrict__ cnt) {
  int i = blockIdx.x * 256 + threadIdx.x;
  if (i < N) atomicAdd(&cnt[lab[i]], 1);
}

__global__ void hg_clu_scan(const int* __restrict__ cnt, int* __restrict__ coff) {
  __shared__ int s[256];
  int t = threadIdx.x;
  int v0 = cnt[t];
  s[t] = v0;
  __syncthreads();
  for (int ofs = 1; ofs < 256; ofs <<= 1) {
    int v = (t >= ofs) ? s[t - ofs] : 0;
    __syncthreads();
    s[t] += v;
    __syncthreads();
  }
  coff[t + 1] = s[t];
  if (t == 0) coff[0] = 0;
}

__global__ void hg_clu_scatter(const int* __restrict__ lab, const int* __restrict__ coff,
                               int* __restrict__ cur, int* __restrict__ list) {
  int i = blockIdx.x * 256 + threadIdx.x;
  if (i < N) {
    int c = lab[i];
    int p = atomicAdd(&cur[c], 1);
    list[coff[c] + p] = i;
  }
}

// tissue CSR (dst-major) + dinv, single block
__global__ __launch_bounds__(256) void hg_tissue_csr(const int* __restrict__ tsrc, const int* __restrict__ tdst,
                                                     int* __restrict__ toff, int* __restrict__ tlist,
                                                     float* __restrict__ dinv) {
  __shared__ int hst[256], incl[256], pos[256];
  int t = threadIdx.x;
  hst[t] = 0;
  __syncthreads();
  for (int e = t; e < ET; e += 256) atomicAdd(&hst[tdst[e]], 1);
  __syncthreads();
  int v = hst[t];
  dinv[t] = rsqrtf((float)(v + 1));  // +1 self-loop
  incl[t] = v;
  __syncthreads();
  for (int ofs = 1; ofs < 256; ofs <<= 1) {
    int u = (t >= ofs) ? incl[t - ofs] : 0;
    __syncthreads();
    incl[t] += u;
    __syncthreads();
  }
  toff[t + 1] = incl[t];
  if (t == 0) toff[0] = 0;
  pos[t] = incl[t] - v;
  __syncthreads();
  for (int e = t; e < ET; e += 256) {
    int d = tdst[e];
    int p = atomicAdd(&pos[d], 1);
    tlist[p] = tsrc[e];
  }
}

// ---------------- weight transposes ----------------
struct TArgs { const float* src[10]; float* dst[10]; int R[10]; int Cc[10]; };

__global__ __launch_bounds__(256) void hg_transpose(TArgs a) {
  int job = blockIdx.y;
  int R = a.R[job], Cc = a.Cc[job];
  int total = R * Cc;
  const float* s = a.src[job];
  float* d = a.dst[job];
  for (int idx = blockIdx.x * 256 + threadIdx.x; idx < total; idx += gridDim.x * 256) {
    int cI = idx / R, r = idx - cI * R;
    d[idx] = s[r * Cc + cI];  // d[Cc][R] = transpose(s[R][Cc])
  }
}

// ---------------- composite weight precompute ----------------
// Wcomp_t[k][j] = sum_m gatW1[j][m] * Wcp[m][k]  (k in [0,256), j in [0,128))
__global__ __launch_bounds__(256) void hg_pc0(const float* __restrict__ gatW1, const float* __restrict__ Wcp,
                                              const float* __restrict__ bcp, float* __restrict__ Wcompt,
                                              float* __restrict__ bcomp) {
  int j = blockIdx.x, k = threadIdx.x;
  float a = 0.f;
#pragma unroll 4
  for (int m = 0; m < 128; ++m) a = fmaf(gatW1[j * 128 + m], Wcp[m * 256 + k], a);
  Wcompt[k * 128 + j] = a;
  if (k == 0) {
    float b = 0.f;
    for (int m = 0; m < 128; ++m) b = fmaf(gatW1[j * 128 + m], bcp[m], b);
    bcomp[j] = b;
  }
}

// A_td[j][k] = sum_p tdWo[j][p]*tdWv[p][k]; bcat[j] = tdWo[j]·tdbv + tdbo[j]
__global__ __launch_bounds__(128) void hg_pc1(const float* __restrict__ tdWo, const float* __restrict__ tdWv,
                                              const float* __restrict__ tdbv, const float* __restrict__ tdbo,
                                              float* __restrict__ A_td, float* __restrict__ Wcat_t,
                                              float* __restrict__ bcat) {
  int j = blockIdx.x, k = threadIdx.x;
  float a = 0.f;
#pragma unroll 4
  for (int p = 0; p < 128; ++p) a = fmaf(tdWo[j * 128 + p], tdWv[p * 128 + k], a);
  A_td[j * 128 + k] = a;
  Wcat_t[k * 896 + j] = a;
  if (k == 0) {
    float b = 0.f;
    for (int p = 0; p < 128; ++p) b = fmaf(tdWo[j * 128 + p], tdbv[p], b);
    bcat[j] = b + tdbo[j];
  }
}

// gi: Wcat_t[k][128+j] = sum_m Wih[j][m]*A_td[m][k] + Wih[j][128+k];  bcat[128+j]=Wih[j,:128]·c_td+bih[j]
// gh: Wcat_t[k][512+j] = sum_m Whh[j][m]*A_td[m][k];                  bcat[512+j]=Whh[j]·c_td+bhh[j]
__global__ __launch_bounds__(128) void hg_pc2(const float* __restrict__ Wih, const float* __restrict__ bih,
                                              const float* __restrict__ Whh, const float* __restrict__ bhh,
                                              const float* __restrict__ A_td, float* __restrict__ Wcat_t,
                                              float* __restrict__ bcat) {
  int jj = blockIdx.x, k = threadIdx.x;
  const float* coef;
  float extra, bb;
  int dcol;
  int j;
  if (jj < 384) {
    j = jj; coef = Wih + (size_t)j * 256; extra = Wih[(size_t)j * 256 + 128 + k]; dcol = 128 + j; bb = bih[j];
  } else {
    j = jj - 384; coef = Whh + (size_t)j * 128; extra = 0.f; dcol = 512 + j; bb = bhh[j];
  }
  float a = 0.f;
#pragma unroll 4
  for (int m = 0; m < 128; ++m) a = fmaf(coef[m], A_td[m * 128 + k], a);
  Wcat_t[k * 896 + dcol] = a + extra;
  if (k == 0) {
    float b = 0.f;
    for (int m = 0; m < 128; ++m) b = fmaf(coef[m], bcat[m], b);
    bcat[dcol] = b + bb;
  }
}

// ---------------- tissue node init: per-cluster feature mean ----------------
__global__ __launch_bounds__(256) void hg_tissue_mean(const float* __restrict__ feat,
                                                      const int* __restrict__ list,
                                                      const int* __restrict__ coff,
                                                      float* __restrict__ tx) {
  int c = blockIdx.x, t = threadIdx.x;
  int s0 = coff[c], n = coff[c + 1] - s0;
  float acc = 0.f;
#pragma unroll 4
  for (int i = 0; i < n; ++i) acc += feat[(size_t)list[s0 + i] * F + t];
  tx[c * F + t] = acc / fmaxf((float)n, 1.f);
}

// ---------------- unified GEMM: out[m][col0+j] = sum_k A[m][k]*Wt[k][col0+j] + bias ----------------
// EPI: 0=plain store, 1=store + GAT coef epilogue, 3=KV (y0: satt only no store, y1: store V)
constexpr int EPI_NONE = 0, EPI_COEF = 1, EPI_KV = 3;

template <int K, int EPI>
__global__ __launch_bounds__(256) void hg_gemm(
    const float* __restrict__ A, int M,
    const float* __restrict__ Wt, const float* __restrict__ bias,
    const float* __restrict__ Wt2, const float* __restrict__ bias2,
    int ldw, int nty,
    float* __restrict__ outp, int ldo,
    const float* __restrict__ e0, const float* __restrict__ e1,
    const int* __restrict__ lab,
    float* __restrict__ o0, float* __restrict__ o1,
    int* __restrict__ ticket) {
  __shared__ float Alds[64][68];
  __shared__ float Wlds[64][132];
  __shared__ int sh_tile;
  const int t = threadIdx.x;
  const int tx = t & 15, ty = t >> 4;
  const int ntx = (M + 63) >> 6;
  const int ntiles = ntx * nty;

  for (;;) {
    if (t == 0) sh_tile = atomicAdd(ticket, 1);
    __syncthreads();
    const int tile = sh_tile;
    __syncthreads();
    if (tile >= ntiles) break;
    int xt, yt;
    if (nty > 1) { yt = tile % nty; xt = tile / nty; } else { yt = 0; xt = tile; }
    const int m0 = xt * 64;
    const float* Wsel = (EPI == EPI_KV && yt == 1) ? Wt2 : Wt;
    const float* bsel = (EPI == EPI_KV && yt == 1) ? bias2 : bias;
    const int col0 = (EPI == EPI_KV) ? 0 : yt * 128;

    float acc[4][8];
#pragma unroll
    for (int r = 0; r < 4; ++r)
#pragma unroll
      for (int c = 0; c < 8; ++c) acc[r][c] = 0.f;

    for (int kc = 0; kc < K; kc += 64) {
#pragma unroll
      for (int i = 0; i < 4; ++i) {
        int row = ty + i * 16;
        int gm = m0 + row;
        float4 v = make_float4(0.f, 0.f, 0.f, 0.f);
        if (gm < M) v = *(const float4*)&A[(size_t)gm * K + kc + tx * 4];
        *(float4*)&Alds[row][tx * 4] = v;
      }
      {
        int c4 = t & 31, r0 = t >> 5;
#pragma unroll
        for (int i = 0; i < 8; ++i) {
          int row = r0 + i * 8;
          *(float4*)&Wlds[row][c4 * 4] = *(const float4*)&Wsel[(size_t)(kc + row) * ldw + col0 + c4 * 4];
        }
      }
      __syncthreads();
#pragma unroll 4
      for (int k4 = 0; k4 < 16; ++k4) {
        float4 av[4];
#pragma unroll
        for (int r = 0; r < 4; ++r) av[r] = *(const float4*)&Alds[ty * 4 + r][k4 * 4];
#pragma unroll
        for (int kk = 0; kk < 4; ++kk) {
          float4 w0 = *(const float4*)&Wlds[k4 * 4 + kk][tx * 4];
          float4 w1 = *(const float4*)&Wlds[k4 * 4 + kk][64 + tx * 4];
          float wr[8] = {w0.x, w0.y, w0.z, w0.w, w1.x, w1.y, w1.z, w1.w};
#pragma unroll
          for (int r = 0; r < 4; ++r) {
            float a = (kk == 0) ? av[r].x : (kk == 1) ? av[r].y : (kk == 2) ? av[r].z : av[r].w;
#pragma unroll
            for (int c = 0; c < 8; ++c) acc[r][c] = fmaf(a, wr[c], acc[r][c]);
          }
        }
      }
      __syncthreads();
    }

    if (bsel) {
      float bA[8];
#pragma unroll
      for (int c = 0; c < 4; ++c) {
        bA[c] = bsel[col0 + tx * 4 + c];
        bA[4 + c] = bsel[col0 + 64 + tx * 4 + c];
      }
#pragma unroll
      for (int r = 0; r < 4; ++r)
#pragma unroll
        for (int c = 0; c < 8; ++c) acc[r][c] += bA[c];
    }

    const bool do_store = (EPI != EPI_KV) || (yt == 1);
    if (do_store) {
#pragma unroll
      for (int r = 0; r < 4; ++r) {
        int gm = m0 + ty * 4 + r;
        if (gm < M) {
          float* op = outp + (size_t)gm * ldo + col0 + tx * 4;
          *(float4*)op        = make_float4(acc[r][0], acc[r][1], acc[r][2], acc[r][3]);
          *(float4*)(op + 64) = make_float4(acc[r][4], acc[r][5], acc[r][6], acc[r][7]);
        }
      }
    }

    if (EPI == EPI_COEF) {
      float4 s0 = *(const float4*)&e0[tx * 4], s1 = *(const float4*)&e0[64 + tx * 4];
      float4 d0 = *(const float4*)&e1[tx * 4], d1 = *(const float4*)&e1[64 + tx * 4];
#pragma unroll
      for (int r = 0; r < 4; ++r) {
        float psA = acc[r][0] * s0.x + acc[r][1] * s0.y + acc[r][2] * s0.z + acc[r][3] * s0.w;
        float psB = acc[r][4] * s1.x + acc[r][5] * s1.y + acc[r][6] * s1.z + acc[r][7] * s1.w;
        float pdA = acc[r][0] * d0.x + acc[r][1] * d0.y + acc[r][2] * d0.z + acc[r][3] * d0.w;
        float pdB = acc[r][4] * d1.x + acc[r][5] * d1.y + acc[r][6] * d1.z + acc[r][7] * d1.w;
        psA += __shfl_xor(psA, 1); psA += __shfl_xor(psA, 2);
        psB += __shfl_xor(psB, 1); psB += __shfl_xor(psB, 2);
        pdA += __shfl_xor(pdA, 1); pdA += __shfl_xor(pdA, 2);
        pdB += __shfl_xor(pdB, 1); pdB += __shfl_xor(pdB, 2);
        int gm = m0 + ty * 4 + r;
        if ((tx & 3) == 0 && gm < M) {
          int h = tx >> 2;
          o0[(size_t)gm * 8 + h] = psA;
          o0[(size_t)gm * 8 + 4 + h] = psB;
          o1[(size_t)gm * 8 + h] = pdA;
          o1[(size_t)gm * 8 + 4 + h] = pdB;
        }
      }
    }
    if (EPI == EPI_KV && yt == 0) {
#pragma unroll
      for (int r = 0; r < 4; ++r) {
        int gm = m0 + ty * 4 + r;
        int lr = (gm < M) ? lab[gm] : 0;
        float4 q0 = *(const float4*)&e0[(size_t)lr * 128 + tx * 4];
        float4 q1 = *(const float4*)&e0[(size_t)lr * 128 + 64 + tx * 4];
        float psA = acc[r][0] * q0.x + acc[r][1] * q0.y + acc[r][2] * q0.z + acc[r][3] * q0.w;
        float psB = acc[r][4] * q1.x + acc[r][5] * q1.y + acc[r][6] * q1.z + acc[r][7] * q1.w;
        psA += __shfl_xor(psA, 1); psA += __shfl_xor(psA, 2);
        psB += __shfl_xor(psB, 1); psB += __shfl_xor(psB, 2);
        int gm2 = m0 + ty * 4 + r;
        if ((tx & 3) == 0 && gm2 < M) {
          int h = tx >> 2;
          o0[(size_t)gm2 * 8 + h] = psA;
          o0[(size_t)gm2 * 8 + 4 + h] = psB;
        }
      }
    }
  }
}

// ---------------- GAT aggregation (per-dst online softmax) ----------------
#define MAXE 192
__global__ __launch_bounds__(128) void hg_gat_agg(const float* __restrict__ hproj, const float* __restrict__ a_s,
                                                  const float* __restrict__ a_d, const int* __restrict__ remap,
                                                  const int* __restrict__ off, const int* __restrict__ csr,
                                                  const float* __restrict__ bias, float* __restrict__ outh) {
  int node = blockIdx.x;
  int t = threadIdx.x;
  __shared__ int srcs[MAXE];
  __shared__ float slds[MAXE][8];
  __shared__ float red[16][8];
  __shared__ float adl[8], asl[8], cmx[8];
  int o0 = off[node], o1 = off[node + 1];
  int deg = o1 - o0;
  int dl = remap ? remap[node] : node;
  if (t < 8) { adl[t] = a_d[dl * 8 + t]; asl[t] = a_s[dl * 8 + t]; }
  __syncthreads();
  const int h = t >> 4;
  const int g = t >> 3, h8 = t & 7;
  const float adh8 = adl[h8];
  float m = -INFINITY, z = 0.f, acc = 0.f;

  for (int cb = 0; cb < deg; cb += MAXE) {
    int len = min(MAXE, deg - cb);
    for (int e = t; e < len; e += 128) {
      int s = csr[o0 + cb + e];
      srcs[e] = remap ? remap[s] : s;
    }
    __syncthreads();
    float lm = -INFINITY;
    for (int e = g; e < len; e += 16) {
      float s = a_s[srcs[e] * 8 + h8] + adh8;
      s = s > 0.f ? s : 0.2f * s;
      slds[e][h8] = s;
      lm = fmaxf(lm, s);
    }
    red[g][h8] = lm;
    __syncthreads();
    if (t < 8) {
      float m2 = -INFINITY;
#pragma unroll
      for (int i = 0; i < 16; ++i) m2 = fmaxf(m2, red[i][t]);
      cmx[t] = m2;
    }
    __syncthreads();
    float nm = fmaxf(m, cmx[h]);
    float sc = expf(m - nm);
    z *= sc; acc *= sc; m = nm;
#pragma unroll 2
    for (int e = 0; e < len; ++e) {
      float w = expf(slds[e][h] - m);
      acc = fmaf(w, hproj[(size_t)srcs[e] * 128 + t], acc);
      z += w;
    }
    __syncthreads();
  }
  {
    float s = asl[h] + adl[h];
    s = s > 0.f ? s : 0.2f * s;
    float nm = fmaxf(m, s);
    float sc = expf(m - nm);
    z *= sc; acc *= sc; m = nm;
    float w = expf(s - m);
    z += w;
    acc = fmaf(w, hproj[(size_t)dl * 128 + t], acc);
  }
  float o = acc / z + bias[t];
  o = o > 0.f ? o : expm1f(o);
  outh[(size_t)node * 128 + t] = o;
}

// ---------------- tissue GCN (CSR) + fused q projection ----------------
__global__ __launch_bounds__(128) void hg_gcn_q(const float* __restrict__ th, const int* __restrict__ toff,
                                                const int* __restrict__ tlist, const float* __restrict__ dinv,
                                                const float* __restrict__ gcnb, const float* __restrict__ Wqt,
                                                const float* __restrict__ bq, float* __restrict__ tish,
                                                float* __restrict__ q) {
  int c = blockIdx.x, t = threadIdx.x;
  __shared__ float trow[128];
  float dc = dinv[c];
  float acc = th[c * 128 + t] * dc * dc;
  int s0 = toff[c], s1 = toff[c + 1];
  for (int i = s0; i < s1; ++i) {
    int s = tlist[i];
    acc = fmaf(th[s * 128 + t], dinv[s] * dc, acc);
  }
  float vv = fmaxf(acc + gcnb[t], 0.f);
  tish[c * 128 + t] = vv;
  trow[t] = vv;
  __syncthreads();
  float qa = bq[t];
#pragma unroll 4
  for (int kk = 0; kk < 128; ++kk) qa = fmaf(trow[kk], Wqt[kk * 128 + t], qa);
  q[c * 128 + t] = qa * 0.25f;  // 1/sqrt(DH)
}

// ---------------- bottom-up per-cluster softmax + context ----------------
__global__ __launch_bounds__(128) void hg_bu_ctx(const float* __restrict__ s_att, const float* __restrict__ v,
                                                 const int* __restrict__ list, const int* __restrict__ coff,
                                                 float* __restrict__ ctx) {
  int c = blockIdx.x, t = threadIdx.x;
  int s0 = coff[c], n = coff[c + 1] - s0;
  __shared__ float red[16][8];
  __shared__ float mh[8];
  int g = t >> 3, h8 = t & 7;
  float lm = -INFINITY;
  for (int i = g; i < n; i += 16) lm = fmaxf(lm, s_att[(size_t)list[s0 + i] * 8 + h8]);
  red[g][h8] = lm;
  __syncthreads();
  if (t < 8) {
    float m2 = -INFINITY;
#pragma unroll
    for (int i = 0; i < 16; ++i) m2 = fmaxf(m2, red[i][t]);
    mh[t] = m2;
  }
  __syncthreads();
  int h = t >> 4;
  float m = mh[h], z = 0.f, acc = 0.f;
#pragma unroll 4
  for (int i = 0; i < n; ++i) {
    int cell = list[s0 + i];
    float w = expf(s_att[(size_t)cell * 8 + h] - m);
    acc = fmaf(w, v[(size_t)cell * 128 + t], acc);
    z += w;
  }
  ctx[c * 128 + t] = (n > 0) ? acc / z : 0.f;
}

// ---------------- GRU gates from cat-GEMM output ----------------
__global__ __launch_bounds__(256) void hg_gates(const float* __restrict__ o, float* __restrict__ ccell) {
  int idx = blockIdx.x * 256 + threadIdx.x;
  if (idx >= C * 128) return;
  int c = idx >> 7, t = idx & 127;
  const float* row = o + (size_t)c * 896;
  float td = row[t];
  float r = 1.f / (1.f + expf(-(row[128 + t] + row[512 + t])));
  float z = 1.f / (1.f + expf(-(row[256 + t] + row[640 + t])));
  float n = tanhf(row[384 + t] + r * row[768 + t]);
  ccell[idx] = (1.f - z) * n + z * td;
}

// ---------------- readout + classifier ----------------
__global__ __launch_bounds__(256) void hg_readout(const float* __restrict__ ccell2, const float* __restrict__ tish,
                                                  const int* __restrict__ cnt, const float* __restrict__ Wc1t,
                                                  const float* __restrict__ bc1, const float* __restrict__ Wc2t,
                                                  const float* __restrict__ bc2, const float* __restrict__ Wc3,
                                                  const float* __restrict__ bc3, float* __restrict__ outp) {
  __shared__ float emb[512], h1s[256], h2s[128];
  int t = threadIdx.x;
  if (t < 128) {
    float sm = 0.f, mx = -INFINITY;
    for (int c = 0; c < C; ++c) {
      float vv = ccell2[c * 128 + t];
      int n = cnt[c];
      sm += (float)n * vv;
      if (n > 0) mx = fmaxf(mx, vv);
    }
    emb[t] = sm / (float)N;
    emb[128 + t] = mx;
  } else {
    int tt = t - 128;
    float sm = 0.f, mx = -INFINITY;
    for (int c = 0; c < C; ++c) {
      float vv = tish[c * 128 + tt];
      sm += vv;
      mx = fmaxf(mx, vv);
    }
    emb[256 + tt] = sm * (1.f / (float)C);
    emb[384 + tt] = mx;
  }
  __syncthreads();
  float a = bc1[t];
#pragma unroll 4
  for (int kk = 0; kk < 512; ++kk) a = fmaf(emb[kk], Wc1t[kk * 256 + t], a);
  h1s[t] = fmaxf(a, 0.f);
  __syncthreads();
  if (t < 128) {
    float a2 = bc2[t];
#pragma unroll 4
    for (int kk = 0; kk < 256; ++kk) a2 = fmaf(h1s[kk], Wc2t[kk * 128 + t], a2);
    h2s[t] = fmaxf(a2, 0.f);
  }
  __syncthreads();
  if (t < 4) {
    float o = bc3[t];
    for (int kk = 0; kk < 128; ++kk) o = fmaf(h2s[kk], Wc3[t * 128 + kk], o);
    outp[t] = o;
  }
}

// ---------------- host launcher ----------------
extern "C" void kernel_launch(void* const* d_in, const int* in_sizes, int n_in,
                              void* d_out, int out_size, void* d_ws, size_t ws_size,
                              hipStream_t stream) {
  (void)in_sizes; (void)n_in; (void)out_size; (void)ws_size;
  const float* feat  = (const float*)d_in[0];
  const int*   eidx  = (const int*)d_in[1];
  const int*   lab   = (const int*)d_in[2];
  const int*   tidx  = (const int*)d_in[3];
  const float* Wcp   = (const float*)d_in[4];
  const float* bcp   = (const float*)d_in[5];
  const float* Wtp   = (const float*)d_in[6];
  const float* btp   = (const float*)d_in[7];
  const float* gatW  = (const float*)d_in[8];
  const float* gasrc = (const float*)d_in[9];
  const float* gadst = (const float*)d_in[10];
  const float* gatb  = (const float*)d_in[11];
  const float* gcnW  = (const float*)d_in[12];
  const float* gcnb  = (const float*)d_in[13];
  const float* buWq  = (const float*)d_in[14];
  const float* buWk  = (const float*)d_in[15];
  const float* buWv  = (const float*)d_in[16];
  const float* bubq  = (const float*)d_in[17];
  const float* bubk  = (const float*)d_in[18];
  const float* bubv  = (const float*)d_in[19];
  const float* buWo  = (const float*)d_in[20];
  const float* bubo  = (const float*)d_in[21];
  const float* tdWv  = (const float*)d_in[22];
  const float* tdbv  = (const float*)d_in[23];
  const float* tdWo  = (const float*)d_in[24];
  const float* tdbo  = (const float*)d_in[25];
  const float* Wih   = (const float*)d_in[26];
  const float* bih   = (const float*)d_in[27];
  const float* Whh   = (const float*)d_in[28];
  const float* bhh   = (const float*)d_in[29];
  const float* Wc1   = (const float*)d_in[30];
  const float* bc1   = (const float*)d_in[31];
  const float* Wc2   = (const float*)d_in[32];
  const float* bc2   = (const float*)d_in[33];
  const float* Wc3   = (const float*)d_in[34];
  const float* bc3   = (const float*)d_in[35];
  float* outp = (float*)d_out;

  const int* csrc = eidx;
  const int* cdst = eidx + E;
  const int* tsrc = tidx;
  const int* tdst = tidx + ET;

  char* w = (char*)d_ws;
  auto alloc = [&](size_t bytes) -> void* {
    void* p = (void*)w;
    w += (bytes + 255) & ~(size_t)255;
    return p;
  };
  char* cnt0 = w;
  int* deg_cell = (int*)alloc((size_t)N * 4);
  int* cur_cell = (int*)alloc((size_t)N * 4);
  int* clu_cnt  = (int*)alloc((size_t)C * 4);
  int* clu_cur  = (int*)alloc((size_t)C * 4);
  int* tickets  = (int*)alloc(16 * 4);
  size_t cntBytes = (size_t)(w - cnt0);
  int* off_cell = (int*)alloc((size_t)(N + 1) * 4);
  int* btot     = (int*)alloc(64 * 4);
  int* csr      = (int*)alloc((size_t)E * 4);
  int* clu_off  = (int*)alloc((size_t)(C + 1) * 4);
  int* clu_list = (int*)alloc((size_t)N * 4);
  int* toff     = (int*)alloc((size_t)(C + 1) * 4);
  int* tlist    = (int*)alloc((size_t)ET * 4);
  float* dinv   = (float*)alloc((size_t)C * 4);
  float* buf1   = (float*)alloc((size_t)N * 128 * 4);
  float* buf2   = (float*)alloc((size_t)N * 128 * 4);
  float* a_s    = (float*)alloc((size_t)N * 8 * 4);
  float* a_d    = (float*)alloc((size_t)N * 8 * 4);
  float* s_att  = (float*)alloc((size_t)N * 8 * 4);
  float* tx     = (float*)alloc((size_t)C * F * 4);
  float* tish   = (float*)alloc((size_t)C * 128 * 4);
  float* thb    = (float*)alloc((size_t)C * 128 * 4);
  float* qb     = (float*)alloc((size_t)C * 128 * 4);
  float* ctxb   = (float*)alloc((size_t)C * 128 * 4);
  float* ccell  = (float*)alloc((size_t)C * 128 * 4);
  float* hprojc = (float*)alloc((size_t)C * 128 * 4);
  float* a_sc   = (float*)alloc((size_t)C * 8 * 4);
  float* a_dc   = (float*)alloc((size_t)C * 8 * 4);
  float* o896   = (float*)alloc((size_t)C * 896 * 4);
  float* A_td   = (float*)alloc(128 * 128 * 4);
  float* Wcat_t = (float*)alloc(128 * 896 * 4);
  float* bcat   = (float*)alloc(896 * 4);
  float* Wcompt = (float*)alloc(256 * 128 * 4);
  float* bcomp  = (float*)alloc(128 * 4);
  float* Wtpt   = (float*)alloc(256 * 128 * 4);
  float* g1t    = (float*)alloc(128 * 128 * 4);
  float* g2t    = (float*)alloc(128 * 128 * 4);
  float* Wqt    = (float*)alloc(128 * 128 * 4);
  float* Wkt    = (float*)alloc(128 * 128 * 4);
  float* Wvt    = (float*)alloc(128 * 128 * 4);
  float* Wot    = (float*)alloc(128 * 128 * 4);
  float* gatW2t = (float*)alloc(128 * 128 * 4);
  float* Wc1t   = (float*)alloc(512 * 256 * 4);
  float* Wc2t   = (float*)alloc(256 * 128 * 4);

  hipMemsetAsync(cnt0, 0, cntBytes, stream);

  hg_cell_hist<<<(E + 255) / 256, 256, 0, stream>>>(cdst, deg_cell);
  hg_scan1<<<NB, 256, 0, stream>>>(deg_cell, off_cell, btot, N);
  hg_scan2<<<1, 64, 0, stream>>>(btot, off_cell);
  hg_scan3<<<NB, 256, 0, stream>>>(off_cell, btot, N);
  hg_cell_scatter<<<(E + 255) / 256, 256, 0, stream>>>(csrc, cdst, off_cell, cur_cell, csr);
  hg_clu_hist<<<(N + 255) / 256, 256, 0, stream>>>(lab, clu_cnt);
  hg_clu_scan<<<1, 256, 0, stream>>>(clu_cnt, clu_off);
  hg_clu_scatter<<<(N + 255) / 256, 256, 0, stream>>>(lab, clu_off, clu_cur, clu_list);
  hg_tissue_csr<<<1, 256, 0, stream>>>(tsrc, tdst, toff, tlist, dinv);

  TArgs ta;
  ta.src[0] = Wtp;            ta.dst[0] = Wtpt;   ta.R[0] = 128; ta.Cc[0] = 256;
  ta.src[1] = gcnW;           ta.dst[1] = g1t;    ta.R[1] = 128; ta.Cc[1] = 128;
  ta.src[2] = gcnW + 128*128; ta.dst[2] = g2t;    ta.R[2] = 128; ta.Cc[2] = 128;
  ta.src[3] = buWq;           ta.dst[3] = Wqt;    ta.R[3] = 128; ta.Cc[3] = 128;
  ta.src[4] = buWk;           ta.dst[4] = Wkt;    ta.R[4] = 128; ta.Cc[4] = 128;
  ta.src[5] = buWv;           ta.dst[5] = Wvt;    ta.R[5] = 128; ta.Cc[5] = 128;
  ta.src[6] = buWo;           ta.dst[6] = Wot;    ta.R[6] = 128; ta.Cc[6] = 128;
  ta.src[7] = gatW + 128*128; ta.dst[7] = gatW2t; ta.R[7] = 128; ta.Cc[7] = 128;
  ta.src[8] = Wc1;            ta.dst[8] = Wc1t;   ta.R[8] = 256; ta.Cc[8] = 512;
  ta.src[9] = Wc2;            ta.dst[9] = Wc2t;   ta.R[9] = 128; ta.Cc[9] = 256;
  hg_transpose<<<dim3(64, 10), 256, 0, stream>>>(ta);

  hg_pc0<<<128, 256, 0, stream>>>(gatW, Wcp, bcp, Wcompt, bcomp);
  hg_pc1<<<128, 128, 0, stream>>>(tdWo, tdWv, tdbv, tdbo, A_td, Wcat_t, bcat);
  hg_pc2<<<768, 128, 0, stream>>>(Wih, bih, Whh, bhh, A_td, Wcat_t, bcat);

  hg_tissue_mean<<<C, 256, 0, stream>>>(feat, clu_list, clu_off, tx);

  int gBig = 768;  // 3 blocks/CU persistent
  // comp1: hproj_l1 = feat @ Wcomp^T + bcomp, + GAT coef epilogue
  hg_gemm<256, EPI_COEF><<<gBig, 256, 0, stream>>>(feat, N, Wcompt, bcomp, nullptr, nullptr, 128, 1,
                                                   buf2, 128, gasrc, gadst, nullptr, a_s, a_d, tickets + 0);
  // tissue proj
  hg_gemm<256, EPI_NONE><<<4, 256, 0, stream>>>(tx, C, Wtpt, btp, nullptr, nullptr, 128, 1,
                                                tish, 128, nullptr, nullptr, nullptr, nullptr, nullptr, tickets + 1);
  // ---- layer 1 ----
  hg_gat_agg<<<N, 128, 0, stream>>>(buf2, a_s, a_d, nullptr, off_cell, csr, gatb, buf1);
  hg_gemm<128, EPI_NONE><<<4, 256, 0, stream>>>(tish, C, g1t, nullptr, nullptr, nullptr, 128, 1,
                                                thb, 128, nullptr, nullptr, nullptr, nullptr, nullptr, tickets + 2);
  hg_gcn_q<<<C, 128, 0, stream>>>(thb, toff, tlist, dinv, gcnb, Wqt, bubq, tish, qb);
  hg_gemm<128, EPI_KV><<<gBig, 256, 0, stream>>>(buf1, N, Wkt, bubk, Wvt, bubv, 128, 2,
                                                 buf2, 128, qb, nullptr, lab, s_att, nullptr, tickets + 3);
  hg_bu_ctx<<<C, 128, 0, stream>>>(s_att, buf2, clu_list, clu_off, ctxb);
  hg_gemm<128, EPI_NONE><<<4, 256, 0, stream>>>(ctxb, C, Wot, bubo, nullptr, nullptr, 128, 1,
                                                tish, 128, nullptr, nullptr, nullptr, nullptr, nullptr, tickets + 4);
  hg_gemm<128, EPI_NONE><<<28, 256, 0, stream>>>(tish, C, Wcat_t, bcat, nullptr, nullptr, 896, 7,
                                                 o896, 896, nullptr, nullptr, nullptr, nullptr, nullptr, tickets + 5);
  hg_gates<<<128, 256, 0, stream>>>(o896, ccell);
  hg_gemm<128, EPI_COEF><<<4, 256, 0, stream>>>(ccell, C, gatW2t, nullptr, nullptr, nullptr, 128, 1,
                                                hprojc, 128, gasrc + 128, gadst + 128, nullptr, a_sc, a_dc, tickets + 6);
  // ---- layer 2 ----
  hg_gat_agg<<<N, 128, 0, stream>>>(hprojc, a_sc, a_dc, lab, off_cell, csr, gatb + 128, buf1);
  hg_gemm<128, EPI_NONE><<<4, 256, 0, stream>>>(tish, C, g2t, nullptr, nullptr, nullptr, 128, 1,
                                                thb, 128, nullptr, nullptr, nullptr, nullptr, nullptr, tickets + 7);
  hg_gcn_q<<<C, 128, 0, stream>>>(thb, toff, tlist, dinv, gcnb + 128, Wqt, bubq, tish, qb);
  hg_gemm<128, EPI_KV><<<gBig, 256, 0, stream>>>(buf1, N, Wkt, bubk, Wvt, bubv, 128, 2,
                                                 buf2, 128, qb, nullptr, lab, s_att, nullptr, tickets + 8);
  hg_bu_ctx<<<C, 128, 0, stream>>>(s_att, buf2, clu_list, clu_off, ctxb);
  hg_gemm<128, EPI_NONE><<<4, 256, 0, stream>>>(ctxb, C, Wot, bubo, nullptr, nullptr, 128, 1,
                                                tish, 128, nullptr, nullptr, nullptr, nullptr, nullptr, tickets + 9);
  hg_gemm<128, EPI_NONE><<<28, 256, 0, stream>>>(tish, C, Wcat_t, bcat, nullptr, nullptr, 896, 7,
                                                 o896, 896, nullptr, nullptr, nullptr, nullptr, nullptr, tickets + 10);
  hg_gates<<<128, 256, 0, stream>>>(o896, ccell);

  hg_readout<<<1, 256, 0, stream>>>(ccell, tish, clu_cnt, Wc1t, bc1, Wc2t, bc2, Wc3, bc3, outp);
}